// Round 1
// baseline (338.400 us; speedup 1.0000x reference)
//
#include <hip/hip_runtime.h>

#define N_NODES 16384
#define N_EDGES 262144
#define F_IN    128
#define DIM     64
#define N_CLS   40
#define KTERMS  24
#define EPSF    1e-8f

// ---------------- degree count ----------------
__global__ __launch_bounds__(256) void k_degree(const int* __restrict__ dst,
                                                float* __restrict__ cnt) {
    int e = blockIdx.x * 256 + threadIdx.x;
    if (e < N_EDGES) atomicAdd(&cnt[dst[e]], 1.0f);
}

// ---------------- dual projection: p = X@Wl, r = X@Wr ----------------
// X: [N, KDIM], Wl/Wr: [KDIM, 64]. Block = 256 threads = 4 rows x 64 cols.
template<int KDIM>
__global__ __launch_bounds__(256) void k_proj(const float* __restrict__ X,
                                              const float* __restrict__ Wl,
                                              const float* __restrict__ Wr,
                                              float* __restrict__ p,
                                              float* __restrict__ r) {
    __shared__ float sW[KDIM * DIM];
    __shared__ float sx[4][KDIM];
    const int tid  = threadIdx.x;
    const int row0 = blockIdx.x * 4;
    const int rloc = tid >> 6;
    const int c    = tid & 63;

    for (int idx = tid; idx < 4 * KDIM; idx += 256)
        sx[idx / KDIM][idx % KDIM] = X[(size_t)row0 * KDIM + idx];
    for (int idx = tid; idx < KDIM * DIM; idx += 256) sW[idx] = Wl[idx];
    __syncthreads();

    float accl = 0.f;
#pragma unroll 8
    for (int k = 0; k < KDIM; ++k) accl = fmaf(sx[rloc][k], sW[k * DIM + c], accl);
    __syncthreads();

    for (int idx = tid; idx < KDIM * DIM; idx += 256) sW[idx] = Wr[idx];
    __syncthreads();

    float accr = 0.f;
#pragma unroll 8
    for (int k = 0; k < KDIM; ++k) accr = fmaf(sx[rloc][k], sW[k * DIM + c], accr);

    p[(row0 + rloc) * DIM + c] = accl;
    r[(row0 + rloc) * DIM + c] = accr;
}

// ---------------- scatter: agg[dst] += p[src], one wave per edge ----------------
__global__ __launch_bounds__(256) void k_scatter(const int* __restrict__ src,
                                                 const int* __restrict__ dst,
                                                 const float* __restrict__ p,
                                                 float* __restrict__ agg) {
    const long long idx = (long long)blockIdx.x * 256 + threadIdx.x;
    const int e    = (int)(idx >> 6);
    const int lane = (int)(idx & 63);
    if (e < N_EDGES) {
        const int s = src[e], d = dst[e];
        atomicAdd(&agg[d * DIM + lane], p[s * DIM + lane]);
    }
}

// ---------------- combine: h = [relu](agg/max(cnt,1) + b + r) ----------------
__global__ __launch_bounds__(256) void k_combine(const float* __restrict__ agg,
                                                 const float* __restrict__ cnt,
                                                 const float* __restrict__ r,
                                                 const float* __restrict__ b,
                                                 float* __restrict__ h, int relu) {
    int i   = blockIdx.x * 256 + threadIdx.x;  // over N*DIM
    int row = i >> 6, d = i & 63;
    float cdeg = fmaxf(cnt[row], 1.0f);
    float v    = agg[i] / cdeg + b[d] + r[i];
    if (relu) v = fmaxf(v, 0.0f);
    h[i] = v;
}

// ---------------- scores + Taylor moments ----------------
// wave per row; lane d owns h[i][d]. Accumulates M_k = sum w*s^k*h, m_k = sum w*s^k.
__global__ __launch_bounds__(256) void k_moments(const float* __restrict__ h,
                                                 const float* __restrict__ aux,
                                                 float* __restrict__ score,
                                                 float* __restrict__ Mm) {
    const int lane = threadIdx.x & 63;
    const int wid  = threadIdx.x >> 6;
    const int gw   = blockIdx.x * 4 + wid;
    const int nw   = gridDim.x * 4;

    float a   = aux[lane];
    float an2 = a * a;
#pragma unroll
    for (int off = 32; off >= 1; off >>= 1) an2 += __shfl_xor(an2, off);
    const float anorm = fmaxf(sqrtf(an2), EPSF);

    float accM[KTERMS], accm[KTERMS];
#pragma unroll
    for (int k = 0; k < KTERMS; ++k) { accM[k] = 0.f; accm[k] = 0.f; }

    for (int i = gw; i < N_NODES; i += nw) {
        float hv = h[i * DIM + lane];
        float d1 = hv * a, d2 = hv * hv;
#pragma unroll
        for (int off = 32; off >= 1; off >>= 1) {
            d1 += __shfl_xor(d1, off);
            d2 += __shfl_xor(d2, off);
        }
        float s = d1 / (anorm * fmaxf(sqrtf(d2), EPSF));
        if (lane == 0) score[i] = s;
        float t = expf(-s * s);
#pragma unroll
        for (int k = 0; k < KTERMS; ++k) {
            accM[k] = fmaf(t, hv, accM[k]);
            accm[k] += t;
            t *= s;
        }
    }

    __shared__ float sM[KTERMS][DIM];
    __shared__ float sm[KTERMS];
    if (wid == 0) {
#pragma unroll
        for (int k = 0; k < KTERMS; ++k) sM[k][lane] = accM[k];
        if (lane == 0)
            for (int k = 0; k < KTERMS; ++k) sm[k] = accm[k];
    }
    __syncthreads();
    if (wid != 0) {
        for (int k = 0; k < KTERMS; ++k) atomicAdd(&sM[k][lane], accM[k]);
        if (lane == 0)
            for (int k = 0; k < KTERMS; ++k) atomicAdd(&sm[k], accm[k]);
    }
    __syncthreads();
    if (wid == 0) {
        for (int k = 0; k < KTERMS; ++k) atomicAdd(&Mm[k * DIM + lane], sM[k][lane]);
        if (lane < KTERMS) atomicAdd(&Mm[KTERMS * DIM + lane], sm[lane]);
    }
}

// ---------------- z from moments ----------------
__global__ __launch_bounds__(256) void k_z(const float* __restrict__ score,
                                           const float* __restrict__ Mm,
                                           float* __restrict__ z) {
    __shared__ float sM[KTERMS * DIM];
    __shared__ float sm[KTERMS];
    const int tid = threadIdx.x;
    for (int idx = tid; idx < KTERMS * DIM; idx += 256) sM[idx] = Mm[idx];
    if (tid < KTERMS) sm[tid] = Mm[KTERMS * DIM + tid];
    __syncthreads();

    const int lane = tid & 63, wid = tid >> 6;
    int gw = blockIdx.x * 4 + wid, nw = gridDim.x * 4;
    for (int i = gw; i < N_NODES; i += nw) {
        const float s2 = 2.f * score[i];
        float c = 1.f, num = 0.f, den = 0.f;
#pragma unroll
        for (int k = 0; k < KTERMS; ++k) {
            num = fmaf(c, sM[k * DIM + lane], num);
            den = fmaf(c, sm[k], den);
            c *= s2 * (1.0f / (float)(k + 1));
        }
        z[i * DIM + lane] = num / den;
    }
}

// ---------------- classifier: out = [h,z] @ Wc + bc ----------------
__global__ __launch_bounds__(256) void k_cls(const float* __restrict__ h,
                                             const float* __restrict__ z,
                                             const float* __restrict__ Wc,
                                             const float* __restrict__ bc,
                                             float* __restrict__ out) {
    __shared__ float sW[2 * DIM * N_CLS];
    __shared__ float sb[N_CLS];
    const int tid = threadIdx.x;
    for (int idx = tid; idx < 2 * DIM * N_CLS; idx += 256) sW[idx] = Wc[idx];
    if (tid < N_CLS) sb[tid] = bc[tid];
    __syncthreads();

    const int lane = tid & 63, wid = tid >> 6;
    int gw = blockIdx.x * 4 + wid, nw = gridDim.x * 4;
    for (int i = gw; i < N_NODES; i += nw) {
        if (lane < N_CLS) {
            float acc = sb[lane];
#pragma unroll 8
            for (int k = 0; k < DIM; ++k)
                acc = fmaf(h[i * DIM + k], sW[k * N_CLS + lane], acc);
#pragma unroll 8
            for (int k = 0; k < DIM; ++k)
                acc = fmaf(z[i * DIM + k], sW[(DIM + k) * N_CLS + lane], acc);
            out[i * N_CLS + lane] = acc;
        }
    }
}

extern "C" void kernel_launch(void* const* d_in, const int* in_sizes, int n_in,
                              void* d_out, int out_size, void* d_ws, size_t ws_size,
                              hipStream_t stream) {
    const float* x   = (const float*)d_in[0];
    const int*   ei  = (const int*)d_in[1];
    const float* W1l = (const float*)d_in[2];
    const float* b1  = (const float*)d_in[3];
    const float* W1r = (const float*)d_in[4];
    const float* W2l = (const float*)d_in[5];
    const float* b2  = (const float*)d_in[6];
    const float* W2r = (const float*)d_in[7];
    const float* aux = (const float*)d_in[8];
    const float* Wc  = (const float*)d_in[9];
    const float* bc  = (const float*)d_in[10];
    float*       out = (float*)d_out;

    const int* src = ei;
    const int* dst = ei + N_EDGES;

    float*       W  = (float*)d_ws;
    const size_t ND = (size_t)N_NODES * DIM;
    float* h1    = W;
    float* hh    = W + ND;
    float* zz    = W + 2 * ND;
    float* pp    = W + 3 * ND;
    float* rr    = W + 4 * ND;
    float* agg   = W + 5 * ND;
    float* cnt   = W + 6 * ND;
    float* score = cnt + N_NODES;
    float* Mm    = score + N_NODES;

    hipMemsetAsync(cnt, 0, N_NODES * sizeof(float), stream);
    hipMemsetAsync(Mm, 0, KTERMS * (DIM + 1) * sizeof(float), stream);
    hipMemsetAsync(agg, 0, ND * sizeof(float), stream);

    k_degree<<<N_EDGES / 256, 256, 0, stream>>>(dst, cnt);
    k_proj<F_IN><<<N_NODES / 4, 256, 0, stream>>>(x, W1l, W1r, pp, rr);
    k_scatter<<<(N_EDGES * 64) / 256, 256, 0, stream>>>(src, dst, pp, agg);
    k_combine<<<(N_NODES * DIM) / 256, 256, 0, stream>>>(agg, cnt, rr, b1, h1, 1);

    k_proj<DIM><<<N_NODES / 4, 256, 0, stream>>>(h1, W2l, W2r, pp, rr);
    hipMemsetAsync(agg, 0, ND * sizeof(float), stream);
    k_scatter<<<(N_EDGES * 64) / 256, 256, 0, stream>>>(src, dst, pp, agg);
    k_combine<<<(N_NODES * DIM) / 256, 256, 0, stream>>>(agg, cnt, rr, b2, hh, 0);

    k_moments<<<128, 256, 0, stream>>>(hh, aux, score, Mm);
    k_z<<<1024, 256, 0, stream>>>(score, Mm, zz);
    k_cls<<<1024, 256, 0, stream>>>(hh, zz, Wc, bc, out);
}

// Round 2
// 229.778 us; speedup vs baseline: 1.4727x; 1.4727x over previous
//
#include <hip/hip_runtime.h>

#define N_NODES 16384
#define N_EDGES 262144
#define F_IN    128
#define DIM     64
#define N_CLS   40
#define KTERMS  24
#define EPSF    1e-8f

// ---------------- degree count (int) ----------------
__global__ __launch_bounds__(256) void k_degree(const int* __restrict__ dst,
                                                int* __restrict__ deg) {
    int e = blockIdx.x * 256 + threadIdx.x;
    if (e < N_EDGES) atomicAdd(&deg[dst[e]], 1);
}

// ---------------- exclusive prefix scan over 16384 ints, one block ----------------
__global__ __launch_bounds__(1024) void k_scan(const int* __restrict__ deg,
                                               int* __restrict__ base,
                                               int* __restrict__ offs) {
    const int tid = threadIdx.x, lane = tid & 63, w = tid >> 6;  // 16 waves
    int loc[16];
    int s = 0;
    const int b0 = tid * 16;
#pragma unroll
    for (int k = 0; k < 16; ++k) { loc[k] = s; s += deg[b0 + k]; }
    // wave-inclusive scan of s
    int v = s;
#pragma unroll
    for (int off = 1; off < 64; off <<= 1) {
        int t = __shfl_up(v, off);
        if (lane >= off) v += t;
    }
    __shared__ int wsum[16];
    if (lane == 63) wsum[w] = v;
    __syncthreads();
    if (w == 0 && lane < 16) {
        int x = wsum[lane];
#pragma unroll
        for (int off = 1; off < 16; off <<= 1) {
            int t = __shfl_up(x, off);
            if (lane >= off) x += t;
        }
        wsum[lane] = x;
    }
    __syncthreads();
    const int wbase = (w == 0) ? 0 : wsum[w - 1];
    const int excl  = wbase + v - s;
#pragma unroll
    for (int k = 0; k < 16; ++k) {
        int bb = excl + loc[k];
        base[b0 + k] = bb;
        offs[b0 + k] = bb;
    }
}

// ---------------- bucket edges by dst ----------------
__global__ __launch_bounds__(256) void k_bucket(const int* __restrict__ src,
                                                const int* __restrict__ dst,
                                                int* __restrict__ offs,
                                                int* __restrict__ ssrc) {
    int e = blockIdx.x * 256 + threadIdx.x;
    if (e < N_EDGES) {
        int pos = atomicAdd(&offs[dst[e]], 1);
        ssrc[pos] = src[e];
    }
}

// ---------------- dual projection: p = X@Wl, r = X@Wr (weights persistent in LDS) ----------------
// wave handles 4 rows; per-wave x staging (no block barriers in main loop).
template<int KDIM>
__global__ __launch_bounds__(256) void k_proj(const float* __restrict__ X,
                                              const float* __restrict__ Wl,
                                              const float* __restrict__ Wr,
                                              float* __restrict__ p,
                                              float* __restrict__ r) {
    __shared__ float sWl[KDIM * DIM];
    __shared__ float sWr[KDIM * DIM];
    __shared__ float sx[4][4][KDIM];  // [wave][row][k]
    const int tid = threadIdx.x, lane = tid & 63, w = tid >> 6;
    for (int idx = tid; idx < KDIM * DIM; idx += 256) {
        sWl[idx] = Wl[idx];
        sWr[idx] = Wr[idx];
    }
    __syncthreads();
    const int nw = gridDim.x * 4;
    for (int g = blockIdx.x * 4 + w; g < N_NODES / 4; g += nw) {
        const int row0 = g * 4;
        const float4* xs = (const float4*)(X + (size_t)row0 * KDIM);
        float4* sd = (float4*)&sx[w][0][0];
#pragma unroll
        for (int idx = lane; idx < KDIM; idx += 64) sd[idx] = xs[idx];
        float accl[4] = {0.f, 0.f, 0.f, 0.f};
        float accr[4] = {0.f, 0.f, 0.f, 0.f};
#pragma unroll 16
        for (int k = 0; k < KDIM; ++k) {
            const float wl = sWl[k * DIM + lane];
            const float wr = sWr[k * DIM + lane];
#pragma unroll
            for (int j = 0; j < 4; ++j) {
                const float xv = sx[w][j][k];
                accl[j] = fmaf(xv, wl, accl[j]);
                accr[j] = fmaf(xv, wr, accr[j]);
            }
        }
#pragma unroll
        for (int j = 0; j < 4; ++j) {
            p[(size_t)(row0 + j) * DIM + lane] = accl[j];
            r[(size_t)(row0 + j) * DIM + lane] = accr[j];
        }
    }
}

// ---------------- CSR gather + combine: h = [relu](mean_j p[src_j] + b + r) ----------------
__global__ __launch_bounds__(256) void k_gather(const int* __restrict__ ssrc,
                                                const int* __restrict__ base,
                                                const int* __restrict__ deg,
                                                const float* __restrict__ p,
                                                const float* __restrict__ r,
                                                const float* __restrict__ b,
                                                float* __restrict__ h, int relu) {
    const int lane = threadIdx.x & 63, w = threadIdx.x >> 6;
    const int node = blockIdx.x * 4 + w;
    if (node >= N_NODES) return;
    const int s0 = base[node];
    const int d  = deg[node];
    float acc = 0.f;
    for (int j0 = 0; j0 < d; j0 += 64) {
        const int m  = min(64, d - j0);
        const int eid = (lane < m) ? ssrc[s0 + j0 + lane] : 0;
        for (int t = 0; t < m; ++t) {
            const int s = __shfl(eid, t);
            acc += p[(size_t)s * DIM + lane];
        }
    }
    float v = acc / fmaxf((float)d, 1.0f) + b[lane] + r[(size_t)node * DIM + lane];
    if (relu) v = fmaxf(v, 0.0f);
    h[(size_t)node * DIM + lane] = v;
}

// ---------------- scores + Taylor moments ----------------
__global__ __launch_bounds__(256) void k_moments(const float* __restrict__ h,
                                                 const float* __restrict__ aux,
                                                 float* __restrict__ score,
                                                 float* __restrict__ Mm) {
    const int lane = threadIdx.x & 63;
    const int wid  = threadIdx.x >> 6;
    const int gw   = blockIdx.x * 4 + wid;
    const int nw   = gridDim.x * 4;

    float a   = aux[lane];
    float an2 = a * a;
#pragma unroll
    for (int off = 32; off >= 1; off >>= 1) an2 += __shfl_xor(an2, off);
    const float anorm = fmaxf(sqrtf(an2), EPSF);

    float accM[KTERMS], accm[KTERMS];
#pragma unroll
    for (int k = 0; k < KTERMS; ++k) { accM[k] = 0.f; accm[k] = 0.f; }

    for (int i = gw; i < N_NODES; i += nw) {
        float hv = h[(size_t)i * DIM + lane];
        float d1 = hv * a, d2 = hv * hv;
#pragma unroll
        for (int off = 32; off >= 1; off >>= 1) {
            d1 += __shfl_xor(d1, off);
            d2 += __shfl_xor(d2, off);
        }
        float s = d1 / (anorm * fmaxf(sqrtf(d2), EPSF));
        if (lane == 0) score[i] = s;
        float t = expf(-s * s);
#pragma unroll
        for (int k = 0; k < KTERMS; ++k) {
            accM[k] = fmaf(t, hv, accM[k]);
            accm[k] += t;
            t *= s;
        }
    }

    __shared__ float sM[KTERMS][DIM];
    __shared__ float sm[KTERMS];
    if (wid == 0) {
#pragma unroll
        for (int k = 0; k < KTERMS; ++k) sM[k][lane] = accM[k];
        if (lane == 0)
            for (int k = 0; k < KTERMS; ++k) sm[k] = accm[k];
    }
    __syncthreads();
    if (wid != 0) {
        for (int k = 0; k < KTERMS; ++k) atomicAdd(&sM[k][lane], accM[k]);
        if (lane == 0)
            for (int k = 0; k < KTERMS; ++k) atomicAdd(&sm[k], accm[k]);
    }
    __syncthreads();
    if (wid == 0) {
        for (int k = 0; k < KTERMS; ++k) atomicAdd(&Mm[k * DIM + lane], sM[k][lane]);
        if (lane < KTERMS) atomicAdd(&Mm[KTERMS * DIM + lane], sm[lane]);
    }
}

// ---------------- fused z + classifier ----------------
__global__ __launch_bounds__(256) void k_zcls(const float* __restrict__ score,
                                              const float* __restrict__ Mm,
                                              const float* __restrict__ h,
                                              const float* __restrict__ Wc,
                                              const float* __restrict__ bc,
                                              float* __restrict__ out) {
    __shared__ float sM[KTERMS * DIM];
    __shared__ float sm[KTERMS];
    __shared__ float sW[2 * DIM * N_CLS];
    __shared__ float sb[N_CLS];
    __shared__ float sh[4][DIM];
    __shared__ float sz[4][DIM];
    const int tid = threadIdx.x;
    for (int idx = tid; idx < KTERMS * DIM; idx += 256) sM[idx] = Mm[idx];
    if (tid < KTERMS) sm[tid] = Mm[KTERMS * DIM + tid];
    for (int idx = tid; idx < 2 * DIM * N_CLS; idx += 256) sW[idx] = Wc[idx];
    if (tid < N_CLS) sb[tid] = bc[tid];
    __syncthreads();

    const int lane = tid & 63, w = tid >> 6;
    const int gw = blockIdx.x * 4 + w, nw = gridDim.x * 4;
    for (int i = gw; i < N_NODES; i += nw) {
        const float s2 = 2.f * score[i];
        float c = 1.f, num = 0.f, den = 0.f;
#pragma unroll
        for (int k = 0; k < KTERMS; ++k) {
            num = fmaf(c, sM[k * DIM + lane], num);
            den = fmaf(c, sm[k], den);
            c *= s2 * (1.0f / (float)(k + 1));
        }
        sz[w][lane] = num / den;
        sh[w][lane] = h[(size_t)i * DIM + lane];
        // same-wave LDS write->read; compiler inserts lgkmcnt wait
        if (lane < N_CLS) {
            float acc = sb[lane];
#pragma unroll 8
            for (int k = 0; k < DIM; ++k)
                acc = fmaf(sh[w][k], sW[k * N_CLS + lane], acc);
#pragma unroll 8
            for (int k = 0; k < DIM; ++k)
                acc = fmaf(sz[w][k], sW[(DIM + k) * N_CLS + lane], acc);
            out[(size_t)i * N_CLS + lane] = acc;
        }
    }
}

extern "C" void kernel_launch(void* const* d_in, const int* in_sizes, int n_in,
                              void* d_out, int out_size, void* d_ws, size_t ws_size,
                              hipStream_t stream) {
    const float* x   = (const float*)d_in[0];
    const int*   ei  = (const int*)d_in[1];
    const float* W1l = (const float*)d_in[2];
    const float* b1  = (const float*)d_in[3];
    const float* W1r = (const float*)d_in[4];
    const float* W2l = (const float*)d_in[5];
    const float* b2  = (const float*)d_in[6];
    const float* W2r = (const float*)d_in[7];
    const float* aux = (const float*)d_in[8];
    const float* Wc  = (const float*)d_in[9];
    const float* bc  = (const float*)d_in[10];
    float*       out = (float*)d_out;

    const int* src = ei;
    const int* dst = ei + N_EDGES;

    float*       W  = (float*)d_ws;
    const size_t ND = (size_t)N_NODES * DIM;
    float* pp    = W;
    float* rr    = W + ND;
    float* h1    = W + 2 * ND;
    float* hh    = W + 3 * ND;
    float* score = W + 4 * ND;
    int*   deg   = (int*)(score + N_NODES);
    float* Mm    = (float*)(deg + N_NODES);            // contiguous with deg for one memset
    int*   base  = (int*)(Mm + KTERMS * (DIM + 1));
    int*   offs  = base + N_NODES;
    int*   ssrc  = offs + N_NODES;

    // zero deg + Mm in one shot (they are contiguous)
    hipMemsetAsync(deg, 0, (N_NODES + KTERMS * (DIM + 1)) * sizeof(float), stream);

    k_degree<<<N_EDGES / 256, 256, 0, stream>>>(dst, deg);
    k_scan<<<1, 1024, 0, stream>>>(deg, base, offs);
    k_bucket<<<N_EDGES / 256, 256, 0, stream>>>(src, dst, offs, ssrc);

    k_proj<F_IN><<<512, 256, 0, stream>>>(x, W1l, W1r, pp, rr);
    k_gather<<<N_NODES / 4, 256, 0, stream>>>(ssrc, base, deg, pp, rr, b1, h1, 1);

    k_proj<DIM><<<512, 256, 0, stream>>>(h1, W2l, W2r, pp, rr);
    k_gather<<<N_NODES / 4, 256, 0, stream>>>(ssrc, base, deg, pp, rr, b2, hh, 0);

    k_moments<<<256, 256, 0, stream>>>(hh, aux, score, Mm);
    k_zcls<<<1024, 256, 0, stream>>>(score, Mm, hh, Wc, bc, out);
}